// Round 2
// baseline (11035.688 us; speedup 1.0000x reference)
//
#include <hip/hip_runtime.h>

// ---------------------------------------------------------------------------
// Fused MLP -> 2-layer LSTM scan (T=256) -> MLP head for MI355X (gfx950).
// R2: weights pre-transposed into a cyclic 640KB image (20 x 32KB chunks) and
// STREAMED through a 3-slot LDS ring via global_load_lds (width 16) with
// counted vmcnt + raw s_barrier (T3/T4, m201 pattern). 128 blocks x 512 thr,
// block owns 32 batch rows; mfma_f32_16x16x32_bf16, f32 c-state in VGPRs.
// ---------------------------------------------------------------------------

typedef unsigned short u16;
typedef short bf16x8 __attribute__((ext_vector_type(8)));
typedef float f32x4 __attribute__((ext_vector_type(4)));

#define MFMA16(a, b, c) __builtin_amdgcn_mfma_f32_16x16x32_bf16((a), (b), (c), 0, 0, 0)

#define GLOAD_LDS(gp, lp) __builtin_amdgcn_global_load_lds( \
    (const __attribute__((address_space(1))) unsigned int*)(const void*)(gp), \
    (__attribute__((address_space(3))) unsigned int*)(void*)(lp), 16, 0, 0)

// counted-vmcnt phase end: certify next chunk, keep deeper prefetch in flight
#define VMCNT_BAR(N) do { \
  asm volatile("s_waitcnt vmcnt(" #N ")" ::: "memory"); \
  __builtin_amdgcn_sched_barrier(0); \
  __builtin_amdgcn_s_barrier(); \
  __builtin_amdgcn_sched_barrier(0); \
} while (0)

// LDS-write visibility barrier WITHOUT draining vmcnt (prefetches keep flying)
#define LGKM_BAR do { \
  asm volatile("s_waitcnt lgkmcnt(0)" ::: "memory"); \
  __builtin_amdgcn_sched_barrier(0); \
  __builtin_amdgcn_s_barrier(); \
  __builtin_amdgcn_sched_barrier(0); \
} while (0)

__device__ __forceinline__ u16 f2bf(float f) {
  union { float f; unsigned u; } v; v.f = f;
  unsigned r = (v.u + 0x7FFFu + ((v.u >> 16) & 1u)) >> 16;  // RNE
  return (u16)r;
}
__device__ __forceinline__ float fsig(float x) { return 1.0f / (1.0f + __expf(-x)); }
__device__ __forceinline__ float ftanh(float x) { return 2.0f / (1.0f + __expf(-2.0f * x)) - 1.0f; }

// ---- ws layout ------------------------------------------------------------
// u16 idx 0 .. 327679   : cyclic weight image, 20 chunks x 16384 u16 (32KB):
//   chunks 0-7  : Wc1 kt-slices; granule = lg*512 + row (row 0..511, lg 0..3)
//                 value = cat(Wih1,Whh1)[row][kt*32 + lg*8 + e]
//   chunks 8-15 : Wc2 likewise
//   chunk 16    : W_in1 [256x64]; granule = kt*1024 + lg*256 + row (kt 0..1)
//   chunks 17-18: W_in2 [128x256]; granule = kt4*512 + lg*128 + row, K=(h*4+kt4)*32
//   chunk 19    : W_in3 [128x128]; granule = kt*512 + lg*128 + row (kt 0..3)
// u16 327680 : Wo1 [128][128] row-major
// u16 344064 : Wo2 [256][128]
// u16 376832 : Wo3 [32][256]
// f32 idx 192512 : bs1[512] = bih1+bhh1 ; f32 193024 : bs2[512]

__global__ void prep_kernel(const float* __restrict__ Wih1, const float* __restrict__ Whh1,
                            const float* __restrict__ bih1, const float* __restrict__ bhh1,
                            const float* __restrict__ Wih2, const float* __restrict__ Whh2,
                            const float* __restrict__ bih2, const float* __restrict__ bhh2,
                            const float* __restrict__ W_in1, const float* __restrict__ W_in2,
                            const float* __restrict__ W_in3,
                            const float* __restrict__ W_out1, const float* __restrict__ W_out2,
                            const float* __restrict__ W_out3,
                            u16* __restrict__ ws) {
  const int N_total = 386048;
  int stride = gridDim.x * blockDim.x;
  for (int idx = blockIdx.x * blockDim.x + threadIdx.x; idx < N_total; idx += stride) {
    if (idx < 327680) {                      // streamed image
      int chunk = idx >> 14;
      int within = idx & 16383;
      int gran = within >> 3;
      int e = within & 7;
      float v;
      if (chunk < 16) {                      // Wc1 / Wc2 kt-slice
        int lg = gran >> 9, row = gran & 511;
        int kt = chunk & 7;
        int k = kt * 32 + lg * 8 + e;
        const float* Wih = (chunk < 8) ? Wih1 : Wih2;
        const float* Whh = (chunk < 8) ? Whh1 : Whh2;
        v = (k < 128) ? Wih[row * 128 + k] : Whh[row * 128 + (k - 128)];
      } else if (chunk == 16) {              // W_in1
        int kt = gran >> 10, lg = (gran >> 8) & 3, row = gran & 255;
        v = W_in1[row * 64 + kt * 32 + lg * 8 + e];
      } else if (chunk <= 18) {              // W_in2
        int h = chunk - 17;
        int kt4 = gran >> 9, lg = (gran >> 7) & 3, row = gran & 127;
        v = W_in2[row * 256 + (h * 4 + kt4) * 32 + lg * 8 + e];
      } else {                               // W_in3
        int kt = gran >> 9, lg = (gran >> 7) & 3, row = gran & 127;
        v = W_in3[row * 128 + kt * 32 + lg * 8 + e];
      }
      ws[idx] = f2bf(v);
    } else if (idx < 344064) { ws[idx] = f2bf(W_out1[idx - 327680]);
    } else if (idx < 376832) { ws[idx] = f2bf(W_out2[idx - 344064]);
    } else if (idx < 385024) { ws[idx] = f2bf(W_out3[idx - 376832]);
    } else if (idx < 385536) {
      int i = idx - 385024;
      ((float*)ws)[192512 + i] = bih1[i] + bhh1[i];
    } else {
      int i = idx - 385536;
      ((float*)ws)[193024 + i] = bih2[i] + bhh2[i];
    }
  }
}

__global__ __launch_bounds__(512, 2)
void lstm_fused(const float* __restrict__ seq,
                const float* __restrict__ h1_in, const float* __restrict__ c1_in,
                const float* __restrict__ h2_in, const float* __restrict__ c2_in,
                const float* __restrict__ b_in1, const float* __restrict__ b_in2,
                const float* __restrict__ b_in3,
                const float* __restrict__ b_out1, const float* __restrict__ b_out2,
                const float* __restrict__ b_out3,
                const u16* __restrict__ ws, float* __restrict__ out) {
  // LDS 147,456 B total: ring 96K + XB/H1/H2/F2 8K each + F1 16K. 1 block/CU.
  __shared__ u16 ring[3][16384];
  __shared__ u16 XB[4096];
  __shared__ u16 H1s[4096];
  __shared__ u16 H2s[4096];
  __shared__ u16 F1[8192];
  __shared__ u16 F2[4096];

  const int tid = threadIdx.x;
  const int wid = tid >> 6;         // wave 0..7
  const int lane = tid & 63;
  const int lr = lane & 15;
  const int lg = lane >> 4;
  const int b0 = blockIdx.x * 32;

  const float* bs1 = (const float*)ws + 192512;
  const float* bs2 = (const float*)ws + 193024;

  // ---- issue one 32KB chunk: 4 x global_load_lds(16B) per wave ------------
  auto issue_chunk = [&](int gcc) {
    int slot = gcc % 3;
    int cpos = gcc % 20;
    const u16* src = ws + cpos * 16384 + wid * 2048;
    u16* dst = &ring[slot][wid * 2048];
#pragma unroll
    for (int j = 0; j < 4; ++j) {
      GLOAD_LDS(src + j * 512 + lane * 8, dst + j * 512);
    }
  };

  // ---- stage initial h1/h2 (f32 -> bf16, swizzled) ----
  {
    int idx = tid * 8;
    int r = idx >> 7;
    int c8 = (idx & 127) >> 3;
    const float* p1 = h1_in + (size_t)(b0 + r) * 128 + c8 * 8;
    const float* p2 = h2_in + (size_t)(b0 + r) * 128 + c8 * 8;
    bf16x8 v1, v2;
#pragma unroll
    for (int j = 0; j < 8; ++j) { v1[j] = (short)f2bf(p1[j]); v2[j] = (short)f2bf(p2[j]); }
    int g = ((r * 16 + c8) ^ (r & 7)) * 8;
    *(bf16x8*)&H1s[g] = v1;
    *(bf16x8*)&H2s[g] = v2;
  }
  // ---- c-state in registers ----
  float cs1[2][4], cs2[2][4];
#pragma unroll
  for (int rt = 0; rt < 2; ++rt)
#pragma unroll
    for (int j = 0; j < 4; ++j) {
      size_t off = (size_t)(b0 + 16 * rt + lg * 4 + j) * 128 + 16 * wid + lr;
      cs1[rt][j] = c1_in[off];
      cs2[rt][j] = c2_in[off];
    }
  // ---- biases ----
  float bc1[4], bc2[4];
#pragma unroll
  for (int g = 0; g < 4; ++g) {
    bc1[g] = bs1[128 * g + 16 * wid + lr];
    bc2[g] = bs2[128 * g + 16 * wid + lr];
  }
  float bfc1[2] = { b_in1[32 * wid + lr], b_in1[32 * wid + 16 + lr] };
  float bfc2v = b_in2[16 * wid + lr];
  float bfc3v = b_in3[16 * wid + lr];
  __syncthreads();

  // ---- prologue fc(t=0) -> XB, B-fragments read straight from the image ---
  {
    // L1
    f32x4 aL[2][2] = {};
#pragma unroll
    for (int kk = 0; kk < 2; ++kk) {
      bf16x8 a[2];
#pragma unroll
      for (int rt = 0; rt < 2; ++rt) {
        const float* sp = seq + ((size_t)(b0 + 16 * rt + lr) * 256 + 0) * 64 + kk * 32 + lg * 8;
        float4 x0 = *(const float4*)sp; float4 x1 = *(const float4*)(sp + 4);
        bf16x8 av;
        av[0] = (short)f2bf(x0.x); av[1] = (short)f2bf(x0.y);
        av[2] = (short)f2bf(x0.z); av[3] = (short)f2bf(x0.w);
        av[4] = (short)f2bf(x1.x); av[5] = (short)f2bf(x1.y);
        av[6] = (short)f2bf(x1.z); av[7] = (short)f2bf(x1.w);
        a[rt] = av;
      }
#pragma unroll
      for (int ci = 0; ci < 2; ++ci) {
        bf16x8 b = *(const bf16x8*)(ws + 16 * 16384 + (kk * 1024 + lg * 256 + wid * 32 + ci * 16 + lr) * 8);
        aL[0][ci] = MFMA16(a[0], b, aL[0][ci]);
        aL[1][ci] = MFMA16(a[1], b, aL[1][ci]);
      }
    }
#pragma unroll
    for (int rt = 0; rt < 2; ++rt)
#pragma unroll
      for (int ci = 0; ci < 2; ++ci)
#pragma unroll
        for (int j = 0; j < 4; ++j) {
          int r = 16 * rt + lg * 4 + j, c = 32 * wid + 16 * ci + lr;
          F1[(r * 256 + c) ^ ((r & 7) << 3)] = f2bf(fmaxf(aL[rt][ci][j] + bfc1[ci], 0.f));
        }
    __syncthreads();
    // L2
    f32x4 aM[2] = {};
#pragma unroll
    for (int kt = 0; kt < 8; ++kt) {
      bf16x8 a[2];
#pragma unroll
      for (int rt = 0; rt < 2; ++rt) {
        int r = 16 * rt + lr;
        a[rt] = *(const bf16x8*)&F1[((r * 32 + kt * 4 + lg) ^ (r & 7)) * 8];
      }
      const u16* cb = ws + (17 + (kt >> 2)) * 16384;
      bf16x8 b = *(const bf16x8*)(cb + ((kt & 3) * 512 + lg * 128 + wid * 16 + lr) * 8);
      aM[0] = MFMA16(a[0], b, aM[0]);
      aM[1] = MFMA16(a[1], b, aM[1]);
    }
#pragma unroll
    for (int rt = 0; rt < 2; ++rt)
#pragma unroll
      for (int j = 0; j < 4; ++j) {
        int r = 16 * rt + lg * 4 + j, c = 16 * wid + lr;
        F2[(r * 128 + c) ^ ((r & 7) << 3)] = f2bf(fmaxf(aM[rt][j] + bfc2v, 0.f));
      }
    __syncthreads();
    // L3
    f32x4 aN[2] = {};
#pragma unroll
    for (int kt = 0; kt < 4; ++kt) {
      bf16x8 a[2];
#pragma unroll
      for (int rt = 0; rt < 2; ++rt) {
        int r = 16 * rt + lr;
        a[rt] = *(const bf16x8*)&F2[((r * 16 + kt * 4 + lg) ^ (r & 7)) * 8];
      }
      bf16x8 b = *(const bf16x8*)(ws + 19 * 16384 + (kt * 512 + lg * 128 + wid * 16 + lr) * 8);
      aN[0] = MFMA16(a[0], b, aN[0]);
      aN[1] = MFMA16(a[1], b, aN[1]);
    }
#pragma unroll
    for (int rt = 0; rt < 2; ++rt)
#pragma unroll
      for (int j = 0; j < 4; ++j) {
        int r = 16 * rt + lg * 4 + j, c = 16 * wid + lr;
        XB[(r * 128 + c) ^ ((r & 7) << 3)] = f2bf(fmaxf(aN[rt][j] + bfc3v, 0.f));
      }
    __syncthreads();
  }

  // ---- one cell chunk-phase: issue i+2, consume i (no phase-end) ----------
  auto cell_phase = [&](int gcc, int kt, f32x4 (&acc)[2][4], const u16* ab) {
    issue_chunk(gcc + 2);
    const u16* rb = &ring[gcc % 3][0];
    int k4 = (kt & 3) * 4 + lg;
    bf16x8 a0 = *(const bf16x8*)&ab[((lr * 16 + k4) ^ (lr & 7)) * 8];
    bf16x8 a1 = *(const bf16x8*)&ab[(((16 + lr) * 16 + k4) ^ (lr & 7)) * 8];
#pragma unroll
    for (int g4 = 0; g4 < 4; ++g4) {
      bf16x8 b = *(const bf16x8*)&rb[(lg * 512 + g4 * 128 + wid * 16 + lr) * 8];
      acc[0][g4] = MFMA16(a0, b, acc[0][g4]);
      acc[1][g4] = MFMA16(a1, b, acc[1][g4]);
    }
  };

  // ---- ring prologue: preload chunks 0,1 ----
  issue_chunk(0);
  issue_chunk(1);
  VMCNT_BAR(4);          // chunk 0 certified, chunk 1 in flight

  float4 sq[2][2][2];    // seq prefetch for t+1: [kt][rt][half]
  int gc = 0;

  for (int t = 0; t < 256; ++t) {
    // ================= cell1: phases 0..7 (Wc1) =================
    f32x4 acc1[2][4] = {};
#pragma unroll
    for (int kt = 0; kt < 8; ++kt) {
      cell_phase(gc, kt, acc1, (kt < 4) ? XB : H1s);
      VMCNT_BAR(4);
      ++gc;
    }
    // elementwise 1 -> write H1 (new)
#pragma unroll
    for (int rt = 0; rt < 2; ++rt)
#pragma unroll
      for (int j = 0; j < 4; ++j) {
        float gi = acc1[rt][0][j] + bc1[0];
        float gf = acc1[rt][1][j] + bc1[1];
        float gg = acc1[rt][2][j] + bc1[2];
        float go = acc1[rt][3][j] + bc1[3];
        float cn = fsig(gf) * cs1[rt][j] + fsig(gi) * ftanh(gg);
        cs1[rt][j] = cn;
        float hv = fsig(go) * ftanh(cn);
        int r = 16 * rt + lg * 4 + j;
        H1s[(r * 128 + 16 * wid + lr) ^ ((r & 7) << 3)] = f2bf(hv);
      }
    LGKM_BAR;

    // ================= cell2: phases 8..15 (Wc2) =================
    f32x4 acc2[2][4] = {};
#pragma unroll
    for (int kt = 0; kt < 8; ++kt) {
      cell_phase(gc, kt, acc2, (kt < 4) ? H1s : H2s);
      if (kt == 4) {   // prefetch seq rows for t+1 (clamped) into VGPRs
        int t1 = (t + 1 > 255) ? 255 : (t + 1);
#pragma unroll
        for (int kk = 0; kk < 2; ++kk)
#pragma unroll
          for (int rt = 0; rt < 2; ++rt) {
            const float* sp = seq + ((size_t)(b0 + 16 * rt + lr) * 256 + t1) * 64 + kk * 32 + lg * 8;
            sq[kk][rt][0] = *(const float4*)sp;
            sq[kk][rt][1] = *(const float4*)(sp + 4);
          }
      }
      if (kt == 4 || kt == 5) { VMCNT_BAR(12); } else { VMCNT_BAR(4); }
      ++gc;
    }
    // elementwise 2 -> write H2 (new)
#pragma unroll
    for (int rt = 0; rt < 2; ++rt)
#pragma unroll
      for (int j = 0; j < 4; ++j) {
        float gi = acc2[rt][0][j] + bc2[0];
        float gf = acc2[rt][1][j] + bc2[1];
        float gg = acc2[rt][2][j] + bc2[2];
        float go = acc2[rt][3][j] + bc2[3];
        float cn = fsig(gf) * cs2[rt][j] + fsig(gi) * ftanh(gg);
        cs2[rt][j] = cn;
        float hv = fsig(go) * ftanh(cn);
        int r = 16 * rt + lg * 4 + j;
        H2s[(r * 128 + 16 * wid + lr) ^ ((r & 7) << 3)] = f2bf(hv);
      }
    LGKM_BAR;

    // ================= fc(t+1): phases 16..19 =================
    { // phase 16: L1 (W_in1)
      issue_chunk(gc + 2);
      const u16* rb = &ring[gc % 3][0];
      f32x4 aL[2][2] = {};
#pragma unroll
      for (int kk = 0; kk < 2; ++kk) {
        bf16x8 a[2];
#pragma unroll
        for (int rt = 0; rt < 2; ++rt) {
          float4 x0 = sq[kk][rt][0], x1 = sq[kk][rt][1];
          bf16x8 av;
          av[0] = (short)f2bf(x0.x); av[1] = (short)f2bf(x0.y);
          av[2] = (short)f2bf(x0.z); av[3] = (short)f2bf(x0.w);
          av[4] = (short)f2bf(x1.x); av[5] = (short)f2bf(x1.y);
          av[6] = (short)f2bf(x1.z); av[7] = (short)f2bf(x1.w);
          a[rt] = av;
        }
#pragma unroll
        for (int ci = 0; ci < 2; ++ci) {
          bf16x8 b = *(const bf16x8*)&rb[(kk * 1024 + lg * 256 + wid * 32 + ci * 16 + lr) * 8];
          aL[0][ci] = MFMA16(a[0], b, aL[0][ci]);
          aL[1][ci] = MFMA16(a[1], b, aL[1][ci]);
        }
      }
#pragma unroll
      for (int rt = 0; rt < 2; ++rt)
#pragma unroll
        for (int ci = 0; ci < 2; ++ci)
#pragma unroll
          for (int j = 0; j < 4; ++j) {
            int r = 16 * rt + lg * 4 + j, c = 32 * wid + 16 * ci + lr;
            F1[(r * 256 + c) ^ ((r & 7) << 3)] = f2bf(fmaxf(aL[rt][ci][j] + bfc1[ci], 0.f));
          }
      asm volatile("s_waitcnt lgkmcnt(0)" ::: "memory");
      VMCNT_BAR(4);
      ++gc;
    }
    f32x4 aM[2] = {};
    { // phase 17: L2 first half (W_in2 K 0..127)
      issue_chunk(gc + 2);
      const u16* rb = &ring[gc % 3][0];
#pragma unroll
      for (int k4 = 0; k4 < 4; ++k4) {
        int kt = k4;
        bf16x8 a[2];
#pragma unroll
        for (int rt = 0; rt < 2; ++rt) {
          int r = 16 * rt + lr;
          a[rt] = *(const bf16x8*)&F1[((r * 32 + kt * 4 + lg) ^ (r & 7)) * 8];
        }
        bf16x8 b = *(const bf16x8*)&rb[(k4 * 512 + lg * 128 + wid * 16 + lr) * 8];
        aM[0] = MFMA16(a[0], b, aM[0]);
        aM[1] = MFMA16(a[1], b, aM[1]);
      }
      VMCNT_BAR(4);
      ++gc;
    }
    { // phase 18: L2 second half (W_in2 K 128..255) -> F2
      issue_chunk(gc + 2);
      const u16* rb = &ring[gc % 3][0];
#pragma unroll
      for (int k4 = 0; k4 < 4; ++k4) {
        int kt = 4 + k4;
        bf16x8 a[2];
#pragma unroll
        for (int rt = 0; rt < 2; ++rt) {
          int r = 16 * rt + lr;
          a[rt] = *(const bf16x8*)&F1[((r * 32 + kt * 4 + lg) ^ (r & 7)) * 8];
        }
        bf16x8 b = *(const bf16x8*)&rb[(k4 * 512 + lg * 128 + wid * 16 + lr) * 8];
        aM[0] = MFMA16(a[0], b, aM[0]);
        aM[1] = MFMA16(a[1], b, aM[1]);
      }
#pragma unroll
      for (int rt = 0; rt < 2; ++rt)
#pragma unroll
        for (int j = 0; j < 4; ++j) {
          int r = 16 * rt + lg * 4 + j, c = 16 * wid + lr;
          F2[(r * 128 + c) ^ ((r & 7) << 3)] = f2bf(fmaxf(aM[rt][j] + bfc2v, 0.f));
        }
      asm volatile("s_waitcnt lgkmcnt(0)" ::: "memory");
      VMCNT_BAR(4);
      ++gc;
    }
    { // phase 19: L3 (W_in3) -> XB
      issue_chunk(gc + 2);
      const u16* rb = &ring[gc % 3][0];
      f32x4 aN[2] = {};
#pragma unroll
      for (int kt = 0; kt < 4; ++kt) {
        bf16x8 a[2];
#pragma unroll
        for (int rt = 0; rt < 2; ++rt) {
          int r = 16 * rt + lr;
          a[rt] = *(const bf16x8*)&F2[((r * 16 + kt * 4 + lg) ^ (r & 7)) * 8];
        }
        bf16x8 b = *(const bf16x8*)&rb[(kt * 512 + lg * 128 + wid * 16 + lr) * 8];
        aN[0] = MFMA16(a[0], b, aN[0]);
        aN[1] = MFMA16(a[1], b, aN[1]);
      }
#pragma unroll
      for (int rt = 0; rt < 2; ++rt)
#pragma unroll
        for (int j = 0; j < 4; ++j) {
          int r = 16 * rt + lg * 4 + j, c = 16 * wid + lr;
          XB[(r * 128 + c) ^ ((r & 7) << 3)] = f2bf(fmaxf(aN[rt][j] + bfc3v, 0.f));
        }
      asm volatile("s_waitcnt lgkmcnt(0)" ::: "memory");
      VMCNT_BAR(4);
      ++gc;
    }
  }

  // ---- drain pipeline, then head ----
  asm volatile("s_waitcnt vmcnt(0)" ::: "memory");
  __syncthreads();

  const u16* Wo1 = ws + 327680;
  const u16* Wo2 = ws + 344064;
  const u16* Wo3 = ws + 376832;
  { // Y1 = relu(h2 @ Wo1^T + b_out1) -> F2
    f32x4 acc[2] = {};
#pragma unroll
    for (int kt = 0; kt < 4; ++kt) {
      bf16x8 a[2];
#pragma unroll
      for (int rt = 0; rt < 2; ++rt) {
        int r = 16 * rt + lr;
        a[rt] = *(const bf16x8*)&H2s[((r * 16 + kt * 4 + lg) ^ (r & 7)) * 8];
      }
      bf16x8 b = *(const bf16x8*)(Wo1 + (size_t)(16 * wid + lr) * 128 + kt * 32 + lg * 8);
      acc[0] = MFMA16(a[0], b, acc[0]);
      acc[1] = MFMA16(a[1], b, acc[1]);
    }
    float bo1v = b_out1[16 * wid + lr];
#pragma unroll
    for (int rt = 0; rt < 2; ++rt)
#pragma unroll
      for (int j = 0; j < 4; ++j) {
        int r = 16 * rt + lg * 4 + j, c = 16 * wid + lr;
        F2[(r * 128 + c) ^ ((r & 7) << 3)] = f2bf(fmaxf(acc[rt][j] + bo1v, 0.f));
      }
    __syncthreads();
  }
  { // Y2 = relu(Y1 @ Wo2^T + b_out2) -> F1
    f32x4 acc[2][2] = {};
#pragma unroll
    for (int kt = 0; kt < 4; ++kt) {
      bf16x8 a[2];
#pragma unroll
      for (int rt = 0; rt < 2; ++rt) {
        int r = 16 * rt + lr;
        a[rt] = *(const bf16x8*)&F2[((r * 16 + kt * 4 + lg) ^ (r & 7)) * 8];
      }
#pragma unroll
      for (int ci = 0; ci < 2; ++ci) {
        bf16x8 b = *(const bf16x8*)(Wo2 + (size_t)(32 * wid + 16 * ci + lr) * 128 + kt * 32 + lg * 8);
        acc[0][ci] = MFMA16(a[0], b, acc[0][ci]);
        acc[1][ci] = MFMA16(a[1], b, acc[1][ci]);
      }
    }
#pragma unroll
    for (int rt = 0; rt < 2; ++rt)
#pragma unroll
      for (int ci = 0; ci < 2; ++ci)
#pragma unroll
        for (int j = 0; j < 4; ++j) {
          int r = 16 * rt + lg * 4 + j, c = 32 * wid + 16 * ci + lr;
          float v = fmaxf(acc[rt][ci][j] + b_out2[c], 0.f);
          F1[(r * 256 + c) ^ ((r & 7) << 3)] = f2bf(v);
        }
    __syncthreads();
  }
  if (wid < 4) { // Y3 = Y2 @ Wo3^T + b_out3
    int rt = wid >> 1, ci = wid & 1;
    f32x4 acc = {};
#pragma unroll
    for (int kt = 0; kt < 8; ++kt) {
      int r = 16 * rt + lr;
      bf16x8 a = *(const bf16x8*)&F1[((r * 32 + kt * 4 + lg) ^ (r & 7)) * 8];
      bf16x8 b = *(const bf16x8*)(Wo3 + (size_t)(16 * ci + lr) * 256 + kt * 32 + lg * 8);
      acc = MFMA16(a, b, acc);
    }
    float bo3v = b_out3[16 * ci + lr];
#pragma unroll
    for (int j = 0; j < 4; ++j)
      out[(size_t)(b0 + 16 * rt + lg * 4 + j) * 32 + 16 * ci + lr] = acc[j] + bo3v;
  }
}

extern "C" void kernel_launch(void* const* d_in, const int* in_sizes, int n_in,
                              void* d_out, int out_size, void* d_ws, size_t ws_size,
                              hipStream_t stream) {
  (void)in_sizes; (void)n_in; (void)out_size; (void)ws_size;
  const float* seq    = (const float*)d_in[0];
  const float* h1     = (const float*)d_in[1];
  const float* c1     = (const float*)d_in[2];
  const float* h2     = (const float*)d_in[3];
  const float* c2     = (const float*)d_in[4];
  const float* W_in1  = (const float*)d_in[5];
  const float* b_in1  = (const float*)d_in[6];
  const float* W_in2  = (const float*)d_in[7];
  const float* b_in2  = (const float*)d_in[8];
  const float* W_in3  = (const float*)d_in[9];
  const float* b_in3  = (const float*)d_in[10];
  const float* Wih1   = (const float*)d_in[11];
  const float* Whh1   = (const float*)d_in[12];
  const float* bih1   = (const float*)d_in[13];
  const float* bhh1   = (const float*)d_in[14];
  const float* Wih2   = (const float*)d_in[15];
  const float* Whh2   = (const float*)d_in[16];
  const float* bih2   = (const float*)d_in[17];
  const float* bhh2   = (const float*)d_in[18];
  const float* W_out1 = (const float*)d_in[19];
  const float* b_out1 = (const float*)d_in[20];
  const float* W_out2 = (const float*)d_in[21];
  const float* b_out2 = (const float*)d_in[22];
  const float* W_out3 = (const float*)d_in[23];
  const float* b_out3 = (const float*)d_in[24];
  u16* ws = (u16*)d_ws;
  float* out = (float*)d_out;

  hipLaunchKernelGGL(prep_kernel, dim3(512), dim3(256), 0, stream,
                     Wih1, Whh1, bih1, bhh1, Wih2, Whh2, bih2, bhh2,
                     W_in1, W_in2, W_in3, W_out1, W_out2, W_out3, ws);
  hipLaunchKernelGGL(lstm_fused, dim3(128), dim3(512), 0, stream,
                     seq, h1, c1, h2, c2, b_in1, b_in2, b_in3,
                     b_out1, b_out2, b_out3, ws, out);
}